// Round 1
// baseline (545.646 us; speedup 1.0000x reference)
//
#include <hip/hip_runtime.h>
#include <hip/hip_bf16.h>
#include <math.h>

// GAE on MI355X. N=16384 nodes, E=524288 edges.
// Pipeline: CSR build -> GEMM1(+dis scale) -> gather-agg -> BN stats ->
// GEMM2(fused BN1 affine+relu, +dis) -> agg -> BN stats -> z (fp32 + bf16) ->
// heads / adj (bf16 MFMA z z^T) / edge features.
// b1/b2 omitted: BatchNorm mean-subtraction cancels per-column constants.

constexpr int kN = 16384;
constexpr int kE = 524288;
constexpr float kEps = 1e-5f;

typedef __attribute__((ext_vector_type(8))) short short8v;   // 8 x bf16
typedef __attribute__((ext_vector_type(4))) float f32x4;

// ---------------------------------------------------------------- utility
__global__ void zero_kernel(int* counts, float* sums1, float* sums2) {
  int i = blockIdx.x * 256 + threadIdx.x;
  if (i < kN) counts[i] = 0;
  if (i < 256) sums1[i] = 0.f;
  if (i < 128) sums2[i] = 0.f;
}

__global__ void hist_kernel(const int* __restrict__ dst, int* __restrict__ counts) {
  int e = blockIdx.x * 256 + threadIdx.x;
  if (e < kE) atomicAdd(&counts[dst[e]], 1);
}

// Single-block exclusive scan of counts[16384] -> offsets, pos; also dis=rsqrt(deg).
__global__ __launch_bounds__(1024) void scan_kernel(const int* __restrict__ counts,
    int* __restrict__ offsets, int* __restrict__ pos, float* __restrict__ dis) {
  __shared__ int wave_tot[16];
  int tid = threadIdx.x;
  int base = tid * 16;
  int loc[16];
  int s = 0;
#pragma unroll
  for (int i = 0; i < 16; i++) { loc[i] = s; s += counts[base + i]; }
  int lane = tid & 63, wv = tid >> 6;
  int incl = s;
#pragma unroll
  for (int d = 1; d < 64; d <<= 1) {
    int v = __shfl_up(incl, d, 64);
    if (lane >= d) incl += v;
  }
  if (lane == 63) wave_tot[wv] = incl;
  __syncthreads();
  int woff = 0;
  for (int i = 0; i < wv; i++) woff += wave_tot[i];
  int excl = woff + incl - s;
#pragma unroll
  for (int i = 0; i < 16; i++) {
    int o = excl + loc[i];
    offsets[base + i] = o;
    pos[base + i] = o;
    dis[base + i] = rsqrtf((float)counts[base + i] + 1.0f);  // +1 self-loop
  }
}

__global__ void fill_kernel(const int* __restrict__ src, const int* __restrict__ dst,
                            int* __restrict__ pos, int* __restrict__ csr_src) {
  int e = blockIdx.x * 256 + threadIdx.x;
  if (e < kE) {
    int d = dst[e];
    int p = atomicAdd(&pos[d], 1);
    csr_src[p] = src[e];
  }
}

// ---------------------------------------------------------------- fp32 GEMM
// out[row][c] = dis[row] * sum_k a(row,k) * W[k][c]   (K fixed at 128)
// AFFINE: a = relu(A*scale + shift) applied on stage (fused BN+relu).
template <int BC, bool AFFINE>
__global__ __launch_bounds__(256) void gemm_kernel(
    const float* __restrict__ A, const float* __restrict__ W,
    const float* __restrict__ scl, const float* __restrict__ shf,
    const float* __restrict__ dis, float* __restrict__ out) {
  constexpr int NJ = BC / 16;              // cols per thread (stride 16)
  constexpr int WF4 = (32 * BC) / 4 / 256; // float4 stages of W per thread
  __shared__ float xs[64 * 33];            // 64 rows x 32 k, pad->33
  __shared__ float wsh[32 * BC];
  int tid = threadIdx.x;
  int tx = tid & 15, ty = tid >> 4;
  int r0 = blockIdx.x * 64;
  float acc[4][NJ];
#pragma unroll
  for (int r = 0; r < 4; r++)
#pragma unroll
    for (int j = 0; j < NJ; j++) acc[r][j] = 0.f;

  for (int kb = 0; kb < 128; kb += 32) {
    __syncthreads();
#pragma unroll
    for (int q = 0; q < 2; q++) {
      int f = tid + q * 256;
      int row = f >> 3, kq = f & 7;
      float4 v = *(const float4*)(A + (size_t)(r0 + row) * 128 + kb + kq * 4);
      if (AFFINE) {
        float4 s4 = *(const float4*)(scl + kb + kq * 4);
        float4 h4 = *(const float4*)(shf + kb + kq * 4);
        v.x = fmaxf(0.f, fmaf(v.x, s4.x, h4.x));
        v.y = fmaxf(0.f, fmaf(v.y, s4.y, h4.y));
        v.z = fmaxf(0.f, fmaf(v.z, s4.z, h4.z));
        v.w = fmaxf(0.f, fmaf(v.w, s4.w, h4.w));
      }
      int bb = row * 33 + kq * 4;
      xs[bb + 0] = v.x; xs[bb + 1] = v.y; xs[bb + 2] = v.z; xs[bb + 3] = v.w;
    }
#pragma unroll
    for (int q = 0; q < WF4; q++) {
      int f = tid + q * 256;
      int k = f / (BC / 4), cq = f % (BC / 4);
      *(float4*)&wsh[k * BC + cq * 4] =
          *(const float4*)(W + (size_t)(kb + k) * BC + cq * 4);
    }
    __syncthreads();
#pragma unroll
    for (int kk = 0; kk < 32; kk++) {
      float av[4];
#pragma unroll
      for (int r = 0; r < 4; r++) av[r] = xs[(ty * 4 + r) * 33 + kk];
#pragma unroll
      for (int j = 0; j < NJ; j++) {
        float bv = wsh[kk * BC + tx + j * 16];
#pragma unroll
        for (int r = 0; r < 4; r++) acc[r][j] = fmaf(av[r], bv, acc[r][j]);
      }
    }
  }
#pragma unroll
  for (int r = 0; r < 4; r++) {
    int row = r0 + ty * 4 + r;
    float dr = dis[row];
#pragma unroll
    for (int j = 0; j < NJ; j++)
      out[(size_t)row * BC + tx + j * 16] = acc[r][j] * dr;
  }
}

// ---------------------------------------------------------------- aggregation
// t[d][c] = dis[d] * (hs[d][c] + sum_{incoming edges} hs[src][c])
template <int C>
__global__ void agg_kernel(const float* __restrict__ hs, const int* __restrict__ csr_src,
                           const int* __restrict__ offsets, const int* __restrict__ counts,
                           const float* __restrict__ dis, float* __restrict__ t) {
  int d = blockIdx.x;
  int c = threadIdx.x;
  float acc = hs[(size_t)d * C + c];  // self-loop
  int s0 = offsets[d];
  int n = counts[d];
  for (int i = 0; i < n; i++) {
    int s = csr_src[s0 + i];
    acc += hs[(size_t)s * C + c];
  }
  t[(size_t)d * C + c] = acc * dis[d];
}

// ---------------------------------------------------------------- BN
template <int C>
__global__ __launch_bounds__(256) void stats_kernel(const float* __restrict__ t,
                                                    float* __restrict__ sums) {
  constexpr int RP = 256 / C;
  int c = threadIdx.x % C;
  int rr = threadIdx.x / C;
  float s = 0.f, s2 = 0.f;
  for (int r = blockIdx.x * RP + rr; r < kN; r += gridDim.x * RP) {
    float v = t[(size_t)r * C + c];
    s += v;
    s2 += v * v;
  }
  atomicAdd(&sums[c], s);
  atomicAdd(&sums[C + c], s2);
}

template <int C>
__global__ void finalize_kernel(const float* __restrict__ sums, const float* __restrict__ g,
                                const float* __restrict__ b, float* __restrict__ scale,
                                float* __restrict__ shift) {
  int c = threadIdx.x;
  float mean = sums[c] / (float)kN;
  float var = sums[C + c] / (float)kN - mean * mean;
  float inv = rsqrtf(var + kEps);
  float sc = g[c] * inv;
  scale[c] = sc;
  shift[c] = b[c] - mean * sc;
}

// z = relu(t2*scale+shift), stored fp32 and bf16
__global__ void applyz_kernel(const float* __restrict__ t2, const float* __restrict__ scale,
                              const float* __restrict__ shift, float* __restrict__ zf,
                              __hip_bfloat16* __restrict__ zb) {
  int i = blockIdx.x * 256 + threadIdx.x;  // kN*64 total
  int c = i & 63;
  float v = fmaxf(0.f, fmaf(t2[i], scale[c], shift[c]));
  zf[i] = v;
  zb[i] = __float2bfloat16(v);
}

// ---------------------------------------------------------------- heads
__global__ __launch_bounds__(256) void heads_kernel(const float* __restrict__ zf,
    const float* __restrict__ wbin, const float* __restrict__ bbin,
    const float* __restrict__ wmc, const float* __restrict__ bmc,
    const float* __restrict__ wcont, const float* __restrict__ bcont,
    float* __restrict__ out0) {
  __shared__ float wB[640], wM[640], wC[640], bB[16], bM[16], bC[16];
  int tid = threadIdx.x;
  for (int i = tid; i < 640; i += 256) { wB[i] = wbin[i]; wM[i] = wmc[i]; wC[i] = wcont[i]; }
  if (tid < 10) { bB[tid] = bbin[tid]; bM[tid] = bmc[tid]; bC[tid] = bcont[tid]; }
  __syncthreads();
  int n = blockIdx.x * 256 + tid;  // kN divisible by 256*64
  float zr[64];
  const float4* z4 = (const float4*)(zf + (size_t)n * 64);
#pragma unroll
  for (int q = 0; q < 16; q++) {
    float4 v = z4[q];
    zr[4 * q] = v.x; zr[4 * q + 1] = v.y; zr[4 * q + 2] = v.z; zr[4 * q + 3] = v.w;
  }
  float lb[10], lm[10], lc[10];
#pragma unroll
  for (int j = 0; j < 10; j++) { lb[j] = bB[j]; lm[j] = bM[j]; lc[j] = bC[j]; }
#pragma unroll
  for (int k = 0; k < 64; k++) {
    float v = zr[k];
#pragma unroll
    for (int j = 0; j < 10; j++) {
      lb[j] = fmaf(v, wB[k * 10 + j], lb[j]);
      lm[j] = fmaf(v, wM[k * 10 + j], lm[j]);
      lc[j] = fmaf(v, wC[k * 10 + j], lc[j]);
    }
  }
  float* o = out0 + (size_t)n * 30;
#pragma unroll
  for (int j = 0; j < 10; j++) o[j] = 1.f / (1.f + expf(-lb[j]));
  // softmax group 1: cols 0..3
  float m1 = fmaxf(fmaxf(lm[0], lm[1]), fmaxf(lm[2], lm[3]));
  float e1[4], s1 = 0.f;
#pragma unroll
  for (int j = 0; j < 4; j++) { e1[j] = expf(lm[j] - m1); s1 += e1[j]; }
#pragma unroll
  for (int j = 0; j < 4; j++) o[10 + j] = e1[j] / s1;
  // softmax group 2: cols 4..9
  float m2 = lm[4];
#pragma unroll
  for (int j = 5; j < 10; j++) m2 = fmaxf(m2, lm[j]);
  float e2[6], s2 = 0.f;
#pragma unroll
  for (int j = 0; j < 6; j++) { e2[j] = expf(lm[4 + j] - m2); s2 += e2[j]; }
#pragma unroll
  for (int j = 0; j < 6; j++) o[14 + j] = e2[j] / s2;
#pragma unroll
  for (int j = 0; j < 10; j++) o[20 + j] = lc[j];
}

// ---------------------------------------------------------------- adj = z z^T (bf16 MFMA)
// Block: 256 thr = 4 waves, tile 128x128; wave tile 64x64 = 4x4 frags of 16x16, K=64.
// mfma_f32_16x16x32_bf16 layouts: A[m][k]: lane=m+16*(k/8), elem k%8 (same for B[k][n]
// with n=lane&15). C/D: col=lane&15, row=(lane>>4)*4+reg.
__global__ __launch_bounds__(256) void adj_kernel(const short* __restrict__ zb,
                                                  float* __restrict__ adj) {
  int tid = threadIdx.x;
  int wid = tid >> 6, lane = tid & 63;
  int i0 = blockIdx.x * 128 + (wid >> 1) * 64;
  int j0 = blockIdx.y * 128 + (wid & 1) * 64;
  int lr = lane & 15, lg = lane >> 4;
  short8v a[4][2], b[4][2];
#pragma unroll
  for (int mt = 0; mt < 4; mt++)
#pragma unroll
    for (int ks = 0; ks < 2; ks++)
      a[mt][ks] = *(const short8v*)(zb + (size_t)(i0 + mt * 16 + lr) * 64 + ks * 32 + lg * 8);
#pragma unroll
  for (int nt = 0; nt < 4; nt++)
#pragma unroll
    for (int ks = 0; ks < 2; ks++)
      b[nt][ks] = *(const short8v*)(zb + (size_t)(j0 + nt * 16 + lr) * 64 + ks * 32 + lg * 8);
  f32x4 acc[4][4];
#pragma unroll
  for (int mt = 0; mt < 4; mt++)
#pragma unroll
    for (int nt = 0; nt < 4; nt++) {
      f32x4 zz = {0.f, 0.f, 0.f, 0.f};
      acc[mt][nt] = zz;
    }
#pragma unroll
  for (int ks = 0; ks < 2; ks++)
#pragma unroll
    for (int mt = 0; mt < 4; mt++)
#pragma unroll
      for (int nt = 0; nt < 4; nt++)
        acc[mt][nt] = __builtin_amdgcn_mfma_f32_16x16x32_bf16(a[mt][ks], b[nt][ks],
                                                              acc[mt][nt], 0, 0, 0);
#pragma unroll
  for (int mt = 0; mt < 4; mt++)
#pragma unroll
    for (int nt = 0; nt < 4; nt++)
#pragma unroll
      for (int r = 0; r < 4; r++)
        adj[(size_t)(i0 + mt * 16 + lg * 4 + r) * kN + (j0 + nt * 16 + lr)] =
            acc[mt][nt][r];
}

// ---------------------------------------------------------------- edge features
__global__ __launch_bounds__(256) void edge_kernel(const float* __restrict__ zf,
    const int* __restrict__ srcs, const int* __restrict__ dsts,
    const float* __restrict__ we, const float* __restrict__ be,
    float* __restrict__ eout) {
  __shared__ float w[2048];  // 128 x 16
  __shared__ float bb[16];
  int tid = threadIdx.x;
  for (int i = tid; i < 2048; i += 256) w[i] = we[i];
  if (tid < 16) bb[tid] = be[tid];
  __syncthreads();
  int e = blockIdx.x * 256 + tid;  // kE divisible by 256
  int s = srcs[e], d = dsts[e];
  float acc[16];
#pragma unroll
  for (int f = 0; f < 16; f++) acc[f] = bb[f];
  const float4* zs = (const float4*)(zf + (size_t)s * 64);
#pragma unroll 4
  for (int q = 0; q < 16; q++) {
    float4 v = zs[q];
    const float* wk = &w[q * 64];
#pragma unroll
    for (int f = 0; f < 16; f++) acc[f] = fmaf(v.x, wk[f], acc[f]);
#pragma unroll
    for (int f = 0; f < 16; f++) acc[f] = fmaf(v.y, wk[16 + f], acc[f]);
#pragma unroll
    for (int f = 0; f < 16; f++) acc[f] = fmaf(v.z, wk[32 + f], acc[f]);
#pragma unroll
    for (int f = 0; f < 16; f++) acc[f] = fmaf(v.w, wk[48 + f], acc[f]);
  }
  const float4* zd = (const float4*)(zf + (size_t)d * 64);
#pragma unroll 4
  for (int q = 0; q < 16; q++) {
    float4 v = zd[q];
    const float* wk = &w[1024 + q * 64];
#pragma unroll
    for (int f = 0; f < 16; f++) acc[f] = fmaf(v.x, wk[f], acc[f]);
#pragma unroll
    for (int f = 0; f < 16; f++) acc[f] = fmaf(v.y, wk[16 + f], acc[f]);
#pragma unroll
    for (int f = 0; f < 16; f++) acc[f] = fmaf(v.z, wk[32 + f], acc[f]);
#pragma unroll
    for (int f = 0; f < 16; f++) acc[f] = fmaf(v.w, wk[48 + f], acc[f]);
  }
  float4* o4 = (float4*)(eout + (size_t)e * 16);
  o4[0] = make_float4(acc[0], acc[1], acc[2], acc[3]);
  o4[1] = make_float4(acc[4], acc[5], acc[6], acc[7]);
  o4[2] = make_float4(acc[8], acc[9], acc[10], acc[11]);
  o4[3] = make_float4(acc[12], acc[13], acc[14], acc[15]);
}

// ---------------------------------------------------------------- launch
extern "C" void kernel_launch(void* const* d_in, const int* in_sizes, int n_in,
                              void* d_out, int out_size, void* d_ws, size_t ws_size,
                              hipStream_t stream) {
  const float* x      = (const float*)d_in[0];
  const int*   ei     = (const int*)d_in[1];
  const float* w1     = (const float*)d_in[3];
  const float* bn1_g  = (const float*)d_in[5];
  const float* bn1_b  = (const float*)d_in[6];
  const float* w2     = (const float*)d_in[7];
  const float* bn2_g  = (const float*)d_in[9];
  const float* bn2_b  = (const float*)d_in[10];
  const float* w_bin  = (const float*)d_in[11];
  const float* b_bin  = (const float*)d_in[12];
  const float* w_mc   = (const float*)d_in[13];
  const float* b_mc   = (const float*)d_in[14];
  const float* w_cont = (const float*)d_in[15];
  const float* b_cont = (const float*)d_in[16];
  const float* w_edge = (const float*)d_in[17];
  const float* b_edge = (const float*)d_in[18];

  float* out0 = (float*)d_out;
  float* adj  = out0 + (size_t)kN * 30;
  float* eout = adj + (size_t)kN * kN;

  char* wp = (char*)d_ws;
  auto alloc = [&](size_t bytes) {
    char* p = wp;
    wp += (bytes + 255) & ~(size_t)255;
    return p;
  };
  int*   counts  = (int*)alloc((size_t)kN * 4);
  int*   offsets = (int*)alloc((size_t)kN * 4);
  int*   pos     = (int*)alloc((size_t)kN * 4);
  int*   csr_src = (int*)alloc((size_t)kE * 4);
  float* dis     = (float*)alloc((size_t)kN * 4);
  float* sums1   = (float*)alloc(256 * 4);
  float* sums2   = (float*)alloc(128 * 4);
  float* scale1  = (float*)alloc(128 * 4);
  float* shift1  = (float*)alloc(128 * 4);
  float* scale2  = (float*)alloc(64 * 4);
  float* shift2  = (float*)alloc(64 * 4);
  float* hs1     = (float*)alloc((size_t)kN * 128 * 4);
  float* t1      = (float*)alloc((size_t)kN * 128 * 4);
  float* hs2     = (float*)alloc((size_t)kN * 64 * 4);
  float* t2      = (float*)alloc((size_t)kN * 64 * 4);
  float* zf      = (float*)alloc((size_t)kN * 64 * 4);
  __hip_bfloat16* zb = (__hip_bfloat16*)alloc((size_t)kN * 64 * 2);

  const int* esrc = ei;
  const int* edst = ei + kE;

  zero_kernel<<<dim3(64), dim3(256), 0, stream>>>(counts, sums1, sums2);
  hist_kernel<<<dim3(2048), dim3(256), 0, stream>>>(edst, counts);
  scan_kernel<<<dim3(1), dim3(1024), 0, stream>>>(counts, offsets, pos, dis);
  fill_kernel<<<dim3(2048), dim3(256), 0, stream>>>(esrc, edst, pos, csr_src);

  gemm_kernel<128, false><<<dim3(kN / 64), dim3(256), 0, stream>>>(
      x, w1, nullptr, nullptr, dis, hs1);
  agg_kernel<128><<<dim3(kN), dim3(128), 0, stream>>>(hs1, csr_src, offsets, counts, dis, t1);
  stats_kernel<128><<<dim3(64), dim3(256), 0, stream>>>(t1, sums1);
  finalize_kernel<128><<<dim3(1), dim3(128), 0, stream>>>(sums1, bn1_g, bn1_b, scale1, shift1);

  gemm_kernel<64, true><<<dim3(kN / 64), dim3(256), 0, stream>>>(
      t1, w2, scale1, shift1, dis, hs2);
  agg_kernel<64><<<dim3(kN), dim3(64), 0, stream>>>(hs2, csr_src, offsets, counts, dis, t2);
  stats_kernel<64><<<dim3(64), dim3(256), 0, stream>>>(t2, sums2);
  finalize_kernel<64><<<dim3(1), dim3(64), 0, stream>>>(sums2, bn2_g, bn2_b, scale2, shift2);

  applyz_kernel<<<dim3(kN * 64 / 256), dim3(256), 0, stream>>>(t2, scale2, shift2, zf, zb);

  heads_kernel<<<dim3(kN / 256), dim3(256), 0, stream>>>(
      zf, w_bin, b_bin, w_mc, b_mc, w_cont, b_cont, out0);
  adj_kernel<<<dim3(kN / 128, kN / 128), dim3(256), 0, stream>>>((const short*)zb, adj);
  edge_kernel<<<dim3(kE / 256), dim3(256), 0, stream>>>(zf, esrc, edst, w_edge, b_edge, eout);
}